// Round 3
// baseline (537.631 us; speedup 1.0000x reference)
//
#include <hip/hip_runtime.h>
#include <hip/hip_bf16.h>
#include <stdint.h>

#define B_ 2
#define S_ 2048
#define H_ 1024
#define I_ 2048
#define E_ 8
#define TOK (B_*S_)      // 4096 tokens
#define PAIRS (TOK*2)    // 8192 token-expert pairs
#define MAXBLK 80        // max sum_e ceil(cnt_e/128) = 64+7=71

typedef __bf16 bf16_t;
typedef __bf16 bf16x4 __attribute__((ext_vector_type(4)));
typedef __bf16 bf16x8 __attribute__((ext_vector_type(8)));
typedef float  f32x4  __attribute__((ext_vector_type(4)));
typedef float  f32x16 __attribute__((ext_vector_type(16)));

// async global->LDS, 16B per lane. LDS dest = wave-uniform base + lane*16.
__device__ __forceinline__ void gl_lds16(const bf16_t* g, bf16_t* l) {
    __builtin_amdgcn_global_load_lds(
        (const __attribute__((address_space(1))) unsigned int*)g,
        (__attribute__((address_space(3))) unsigned int*)l, 16, 0, 0);
}

// compiler memory fence (zero instructions) — raw s_barrier has no compiler
// memory semantics; without these, LDS reads/writes can migrate across it.
__device__ __forceinline__ void cfence() { asm volatile("" ::: "memory"); }

// ---------------- Router (+ x -> bf16 cast fused) ----------------
__global__ void router_kernel(const float* __restrict__ x, const float* __restrict__ Wg,
                              int* __restrict__ top2e, float* __restrict__ top2w,
                              int* __restrict__ counts, bf16_t* __restrict__ xb) {
    int wave = threadIdx.x >> 6;
    int lane = threadIdx.x & 63;
    int t = blockIdx.x * 4 + wave;
    if (t >= TOK) return;
    float acc[E_];
#pragma unroll
    for (int e = 0; e < E_; e++) acc[e] = 0.f;
    const float* xrow = x + (size_t)t * H_;
    for (int j = 0; j < H_ / 64; j++) {
        int h = j * 64 + lane;
        float xv = xrow[h];
        const float4* wg = (const float4*)(Wg + (size_t)h * E_);
        float4 w0 = wg[0], w1 = wg[1];
        acc[0] += xv * w0.x; acc[1] += xv * w0.y; acc[2] += xv * w0.z; acc[3] += xv * w0.w;
        acc[4] += xv * w1.x; acc[5] += xv * w1.y; acc[6] += xv * w1.z; acc[7] += xv * w1.w;
    }
    // fused cast: write this token's bf16 row (re-read hits L1/L2)
#pragma unroll
    for (int part = 0; part < 2; part++) {
        int idx = part * 512 + lane * 8;
        float4 v0 = *(const float4*)(xrow + idx);
        float4 v1 = *(const float4*)(xrow + idx + 4);
        bf16x8 ov = { (bf16_t)v0.x, (bf16_t)v0.y, (bf16_t)v0.z, (bf16_t)v0.w,
                      (bf16_t)v1.x, (bf16_t)v1.y, (bf16_t)v1.z, (bf16_t)v1.w };
        *(bf16x8*)(xb + (size_t)t * H_ + idx) = ov;
    }
#pragma unroll
    for (int e = 0; e < E_; e++) {
#pragma unroll
        for (int m = 32; m >= 1; m >>= 1) acc[e] += __shfl_xor(acc[e], m, 64);
    }
    if (lane == 0) {
        float mx = acc[0];
        for (int e = 1; e < E_; e++) mx = fmaxf(mx, acc[e]);
        float p[E_]; float z = 0.f;
        for (int e = 0; e < E_; e++) { p[e] = __expf(acc[e] - mx); z += p[e]; }
        for (int e = 0; e < E_; e++) p[e] /= z;
        int i1 = 0; float p1 = p[0];
        for (int e = 1; e < E_; e++) if (p[e] > p1) { p1 = p[e]; i1 = e; }
        int i2 = -1; float p2 = -1.f;
        for (int e = 0; e < E_; e++) if (e != i1 && p[e] > p2) { p2 = p[e]; i2 = e; }
        float s = p1 + p2 + 1e-8f;
        top2e[t * 2]     = i1; top2e[t * 2 + 1] = i2;
        top2w[t * 2]     = p1 / s; top2w[t * 2 + 1] = p2 / s;
        atomicAdd(&counts[i1], 1);
        atomicAdd(&counts[i2], 1);
    }
}

// ---------------- scan + fill in one block (LDS cursors) ----------------
__global__ __launch_bounds__(256) void scanfill_kernel(
    const int* __restrict__ counts, int* __restrict__ offsets,
    int* __restrict__ blk_e, int* __restrict__ blk_m0, int* __restrict__ nblk,
    const int* __restrict__ top2e, int* __restrict__ pair_tok, int* __restrict__ inv) {
    __shared__ int s_cur[E_];
    if (threadIdx.x == 0) {
        int run = 0, b = 0;
        for (int e = 0; e < E_; e++) {
            offsets[e] = run; s_cur[e] = run;
            int c = counts[e];
            for (int m0 = 0; m0 < c; m0 += 128) { blk_e[b] = e; blk_m0[b] = m0; b++; }
            run += c;
        }
        nblk[0] = b;
    }
    __syncthreads();
    for (int p = threadIdx.x; p < PAIRS; p += 256) {
        int e = top2e[p];
        int pos = atomicAdd(&s_cur[e], 1);
        pair_tok[pos] = p >> 1;
        inv[p] = pos;
    }
}

// ---------------- merged weight transpose-cast ----------------
// z = w*E+e, w in {0:W11, 1:W12, 2:W2}. src [R][C] fp32 -> dst [C][R] bf16.
__global__ __launch_bounds__(256) void wtrans_kernel(
    const float* __restrict__ W11, const float* __restrict__ W12,
    const float* __restrict__ W2,
    bf16_t* __restrict__ W11t, bf16_t* __restrict__ W12t, bf16_t* __restrict__ W2t) {
    __shared__ float tile[64][129];
    int z = blockIdx.y;
    int wsel = z >> 3, e = z & 7;
    const float* sbase; bf16_t* dbase; int R, C, tx, ty;
    if (wsel == 0)      { sbase = W11; dbase = W11t; R = H_; C = I_; }
    else if (wsel == 1) { sbase = W12; dbase = W12t; R = H_; C = I_; }
    else                { sbase = W2;  dbase = W2t;  R = I_; C = H_; }
    if (wsel < 2) { tx = blockIdx.x & 15; ty = blockIdx.x >> 4; }   // 16 x 16
    else          { tx = blockIdx.x & 7;  ty = blockIdx.x >> 3; }   // 8 x 32
    const float* s = sbase + (size_t)e * R * C;
    bf16_t* d = dbase + (size_t)e * R * C;
    int c0 = tx * 128, r0 = ty * 64;
    int t = threadIdx.x;
#pragma unroll
    for (int j = 0; j < 8; j++) {
        int flat = j * 256 + t;          // 0..2047
        int r = flat >> 5;               // 0..63
        int c4 = (flat & 31) * 4;        // 0..124
        float4 v = *(const float4*)(s + (size_t)(r0 + r) * C + c0 + c4);
        tile[r][c4 + 0] = v.x;
        tile[r][c4 + 1] = v.y;
        tile[r][c4 + 2] = v.z;
        tile[r][c4 + 3] = v.w;
    }
    __syncthreads();
#pragma unroll
    for (int j = 0; j < 4; j++) {
        int flat = j * 256 + t;          // 0..1023
        int orow = flat >> 3;            // 0..127 (src col)
        int seg  = (flat & 7) * 8;       // 0..56 (src row base)
        bf16x8 v;
#pragma unroll
        for (int k = 0; k < 8; k++) v[k] = (bf16_t)tile[seg + k][orow];
        *(bf16x8*)(d + (size_t)(c0 + orow) * R + r0 + seg) = v;
    }
}

// ---------------- GEMM1: fused = SiLU(x@W11) * (x@W12) ----------------
// Round-0 skeleton (256 thr / 4 waves 2x2, BM=128, BN=128 i-cols, gate+value
// = 256 B-rows), BK=32 double-buffered LDS (48KB, 2 blocks/CU), counted
// s_waitcnt vmcnt(6). Raw barriers carry explicit fences + lgkmcnt drain
// (round-2 lacked these -> cross-wave LDS race).
__global__ __launch_bounds__(256, 2) void gemm1_kernel(
    const bf16_t* __restrict__ xb,       // [TOK][H]
    const bf16_t* __restrict__ W11t,     // [E][I][H]
    const bf16_t* __restrict__ W12t,     // [E][I][H]
    const int* __restrict__ counts, const int* __restrict__ offsets,
    const int* __restrict__ blk_e, const int* __restrict__ blk_m0,
    const int* __restrict__ nblk,
    const int* __restrict__ pair_tok,
    bf16_t* __restrict__ fused)          // [PAIRS][I]
{
    int by = blockIdx.y;
    if (by >= nblk[0]) return;
    int e = blk_e[by];
    int m0 = blk_m0[by];
    int cnt = counts[e];
    int off = offsets[e];
    int n0 = blockIdx.x * 128;           // i-col base

    __shared__ __align__(16) bf16_t la[2][128 * 32];   // 2 x 8 KB
    __shared__ __align__(16) bf16_t lb[2][256 * 32];   // 2 x 16 KB

    int tid = threadIdx.x;
    int w = tid >> 6, lane = tid & 63;
    int wm = w >> 1, wn = w & 1;
    int lrow4 = lane >> 2;               // 0..15 (LDS row within 16-row group)
    int lcol4 = lane & 3;                // 0..3  (16B slot)
    int sch   = lcol4 ^ (lrow4 & 3);     // swizzled source chunk
    int r32 = lane & 31, khalf = lane >> 5;

    // staging pointers (per-lane global source, +k0 each tile)
    const bf16_t* aptr[2];
    const bf16_t* bptr[4];
#pragma unroll
    for (int it = 0; it < 2; it++) {
        int r = it * 64 + w * 16 + lrow4;     // 0..127
        int grow = m0 + r;
        int tok = pair_tok[off + (grow < cnt ? grow : 0)];
        aptr[it] = xb + (size_t)tok * H_ + sch * 8;
    }
#pragma unroll
    for (int it = 0; it < 4; it++) {
        int r = it * 64 + w * 16 + lrow4;     // 0..255 (0-127 gate, 128-255 value)
        const bf16_t* base = (r < 128)
            ? (W11t + ((size_t)e * I_ + n0 + r) * H_)
            : (W12t + ((size_t)e * I_ + n0 + (r - 128)) * H_);
        bptr[it] = base + sch * 8;
    }

    f32x16 acc[2][4];
#pragma unroll
    for (int a = 0; a < 2; a++)
#pragma unroll
        for (int b = 0; b < 4; b++) acc[a][b] = (f32x16)(0.f);

    // prologue: stage tile 0 into buf0
#pragma unroll
    for (int it = 0; it < 2; it++) gl_lds16(aptr[it], &la[0][(it * 64 + w * 16) * 32]);
#pragma unroll
    for (int it = 0; it < 4; it++) gl_lds16(bptr[it], &lb[0][(it * 64 + w * 16) * 32]);

    const int NT = H_ / 32;              // 32 K-tiles
    for (int t = 0; t < NT; t++) {
        int cur = t & 1;
        if (t + 1 < NT) {
            int nxt = cur ^ 1;
            int ko = (t + 1) * 32;
#pragma unroll
            for (int it = 0; it < 2; it++) gl_lds16(aptr[it] + ko, &la[nxt][(it * 64 + w * 16) * 32]);
#pragma unroll
            for (int it = 0; it < 4; it++) gl_lds16(bptr[it] + ko, &lb[nxt][(it * 64 + w * 16) * 32]);
            // counted wait: tile t's 6 loads done, tile t+1's 6 stay in flight
            asm volatile("s_waitcnt vmcnt(6)" ::: "memory");
        } else {
            asm volatile("s_waitcnt vmcnt(0)" ::: "memory");
        }
        __builtin_amdgcn_s_barrier();        // tile t staged by ALL waves
        __builtin_amdgcn_sched_barrier(0);
        cfence();                            // keep reads below this point

        const bf16_t* A = la[cur];
        const bf16_t* Bb = lb[cur];
#pragma unroll
        for (int t16 = 0; t16 < 2; t16++) {
            int seg = t16 * 2 + khalf;       // 0..3
            bf16x8 af[2], bfr[4];
#pragma unroll
            for (int ms = 0; ms < 2; ms++) {
                int row = wm * 64 + ms * 32 + r32;
                af[ms] = *(const bf16x8*)&A[row * 32 + (seg ^ (r32 & 3)) * 8];
            }
#pragma unroll
            for (int ns = 0; ns < 2; ns++) {
                int browg = wn * 64 + ns * 32 + r32;
                bfr[ns]     = *(const bf16x8*)&Bb[browg * 32 + (seg ^ (r32 & 3)) * 8];
                bfr[ns + 2] = *(const bf16x8*)&Bb[(browg + 128) * 32 + (seg ^ (r32 & 3)) * 8];
            }
#pragma unroll
            for (int ms = 0; ms < 2; ms++)
#pragma unroll
                for (int ns = 0; ns < 4; ns++)
                    acc[ms][ns] = __builtin_amdgcn_mfma_f32_32x32x16_bf16(
                        af[ms], bfr[ns], acc[ms][ns], 0, 0, 0);
        }
        // all my ds_reads serviced BEFORE releasing the buffer
        asm volatile("s_waitcnt lgkmcnt(0)" ::: "memory");
        __builtin_amdgcn_sched_barrier(0);
        __builtin_amdgcn_s_barrier();        // buffer cur may now be overwritten
        cfence();
    }

    // C/D 32x32 layout: col=lane&31, row=(reg&3)+8*(reg>>2)+4*(lane>>5)
#pragma unroll
    for (int ms = 0; ms < 2; ms++) {
#pragma unroll
        for (int ns = 0; ns < 2; ns++) {
            int i = n0 + wn * 64 + ns * 32 + r32;
#pragma unroll
            for (int reg = 0; reg < 16; reg++) {
                int rrow = (reg & 3) + 8 * (reg >> 2) + 4 * khalf;
                int grow = m0 + wm * 64 + ms * 32 + rrow;
                if (grow < cnt) {
                    float g = acc[ms][ns][reg];
                    float v = acc[ms][ns + 2][reg];
                    float f = g * v / (1.f + __expf(-g));
                    fused[(size_t)(off + grow) * I_ + i] = (bf16_t)f;
                }
            }
        }
    }
}

// ---------------- GEMM2: y[slot] = fused[slot] @ W2, bf16 out ----------------
// Same dbuf/counted-vmcnt template: BK=32, 2x16KB LDS, 3 blocks/CU.
__global__ __launch_bounds__(256, 3) void gemm2_kernel(
    const bf16_t* __restrict__ fused,    // [PAIRS][I]
    const bf16_t* __restrict__ W2t,      // [E][H][I]
    const int* __restrict__ counts, const int* __restrict__ offsets,
    const int* __restrict__ blk_e, const int* __restrict__ blk_m0,
    const int* __restrict__ nblk,
    bf16_t* __restrict__ y)              // [PAIRS][H]
{
    int by = blockIdx.y;
    if (by >= nblk[0]) return;
    int e = blk_e[by];
    int m0 = blk_m0[by];
    int cnt = counts[e];
    int off = offsets[e];
    int n0 = blockIdx.x * 128;

    __shared__ __align__(16) bf16_t la[2][128 * 32];   // 2 x 8 KB
    __shared__ __align__(16) bf16_t lb[2][128 * 32];   // 2 x 8 KB

    int tid = threadIdx.x;
    int w = tid >> 6, lane = tid & 63;
    int wm = w >> 1, wn = w & 1;
    int lrow4 = lane >> 2;
    int lcol4 = lane & 3;
    int sch   = lcol4 ^ (lrow4 & 3);
    int r32 = lane & 31, khalf = lane >> 5;

    const bf16_t* aptr[2];
    const bf16_t* bptr[2];
#pragma unroll
    for (int it = 0; it < 2; it++) {
        int r = it * 64 + w * 16 + lrow4;     // 0..127
        int grow = m0 + r;
        if (grow >= cnt) grow = cnt - 1;
        aptr[it] = fused + (size_t)(off + grow) * I_ + sch * 8;
        bptr[it] = W2t + ((size_t)e * H_ + n0 + r) * I_ + sch * 8;
    }

    f32x16 acc[2][2];
#pragma unroll
    for (int a = 0; a < 2; a++)
#pragma unroll
        for (int b = 0; b < 2; b++) acc[a][b] = (f32x16)(0.f);

    // prologue: stage tile 0
#pragma unroll
    for (int it = 0; it < 2; it++) {
        gl_lds16(aptr[it], &la[0][(it * 64 + w * 16) * 32]);
        gl_lds16(bptr[it], &lb[0][(it * 64 + w * 16) * 32]);
    }

    const int NT = I_ / 32;              // 64 K-tiles
    for (int t = 0; t < NT; t++) {
        int cur = t & 1;
        if (t + 1 < NT) {
            int nxt = cur ^ 1;
            int ko = (t + 1) * 32;
#pragma unroll
            for (int it = 0; it < 2; it++) {
                gl_lds16(aptr[it] + ko, &la[nxt][(it * 64 + w * 16) * 32]);
                gl_lds16(bptr[it] + ko, &lb[nxt][(it * 64 + w * 16) * 32]);
            }
            asm volatile("s_waitcnt vmcnt(4)" ::: "memory");
        } else {
            asm volatile("s_waitcnt vmcnt(0)" ::: "memory");
        }
        __builtin_amdgcn_s_barrier();
        __builtin_amdgcn_sched_barrier(0);
        cfence();

        const bf16_t* A = la[cur];
        const bf16_t* Bb = lb[cur];
#pragma unroll
        for (int t16 = 0; t16 < 2; t16++) {
            int seg = t16 * 2 + khalf;
            bf16x8 af[2], bfr[2];
#pragma unroll
            for (int ms = 0; ms < 2; ms++) {
                int row = wm * 64 + ms * 32 + r32;
                af[ms] = *(const bf16x8*)&A[row * 32 + (seg ^ (r32 & 3)) * 8];
            }
#pragma unroll
            for (int ns = 0; ns < 2; ns++) {
                int brow = wn * 64 + ns * 32 + r32;
                bfr[ns] = *(const bf16x8*)&Bb[brow * 32 + (seg ^ (r32 & 3)) * 8];
            }
#pragma unroll
            for (int ms = 0; ms < 2; ms++)
#pragma unroll
                for (int ns = 0; ns < 2; ns++)
                    acc[ms][ns] = __builtin_amdgcn_mfma_f32_32x32x16_bf16(
                        af[ms], bfr[ns], acc[ms][ns], 0, 0, 0);
        }
        asm volatile("s_waitcnt lgkmcnt(0)" ::: "memory");
        __builtin_amdgcn_sched_barrier(0);
        __builtin_amdgcn_s_barrier();
        cfence();
    }

#pragma unroll
    for (int ms = 0; ms < 2; ms++) {
#pragma unroll
        for (int reg = 0; reg < 16; reg++) {
            int rrow = (reg & 3) + 8 * (reg >> 2) + 4 * khalf;
            int grow = m0 + wm * 64 + ms * 32 + rrow;
            if (grow < cnt) {
                int slot = off + grow;
#pragma unroll
                for (int ns = 0; ns < 2; ns++) {
                    int h = n0 + wn * 64 + ns * 32 + r32;
                    y[(size_t)slot * H_ + h] = (bf16_t)acc[ms][ns][reg];
                }
            }
        }
    }
}

// ---------------- combine: out[t] = w1*y[s1] + w2*y[s2] ----------------
__global__ __launch_bounds__(256) void combine_kernel(
    const bf16_t* __restrict__ y, const int* __restrict__ inv,
    const float* __restrict__ top2w, float* __restrict__ out) {
    int t = blockIdx.x;
    int h = threadIdx.x * 4;
    int s1 = inv[t * 2], s2 = inv[t * 2 + 1];
    float w1 = top2w[t * 2], w2 = top2w[t * 2 + 1];
    bf16x4 a = *(const bf16x4*)(y + (size_t)s1 * H_ + h);
    bf16x4 b = *(const bf16x4*)(y + (size_t)s2 * H_ + h);
    f32x4 r;
#pragma unroll
    for (int k = 0; k < 4; k++) r[k] = w1 * (float)a[k] + w2 * (float)b[k];
    *(f32x4*)(out + (size_t)t * H_ + h) = r;
}

// ---------------- host ----------------
extern "C" void kernel_launch(void* const* d_in, const int* in_sizes, int n_in,
                              void* d_out, int out_size, void* d_ws, size_t ws_size,
                              hipStream_t stream) {
    const float* x   = (const float*)d_in[0];
    const float* Wg  = (const float*)d_in[1];
    const float* W11 = (const float*)d_in[2];
    const float* W12 = (const float*)d_in[3];
    const float* W2  = (const float*)d_in[4];
    float* out = (float*)d_out;

    char* ws = (char*)d_ws;
    size_t o = 0;
    auto alloc = [&](size_t bytes) { size_t r = o; o = (o + bytes + 255) & ~(size_t)255; return r; };
    int*    counts   = (int*)(ws + alloc(E_ * 4));
    int*    offsets  = (int*)(ws + alloc(E_ * 4));
    int*    blk_e    = (int*)(ws + alloc(MAXBLK * 4));
    int*    blk_m0   = (int*)(ws + alloc(MAXBLK * 4));
    int*    nblk     = (int*)(ws + alloc(4));
    int*    top2e    = (int*)(ws + alloc(TOK * 2 * 4));
    float*  top2w    = (float*)(ws + alloc(TOK * 2 * 4));
    int*    pair_tok = (int*)(ws + alloc(PAIRS * 4));
    int*    inv      = (int*)(ws + alloc(TOK * 2 * 4));
    bf16_t* xb       = (bf16_t*)(ws + alloc((size_t)TOK * H_ * 2));
    bf16_t* W11t     = (bf16_t*)(ws + alloc((size_t)E_ * I_ * H_ * 2));
    bf16_t* W12t     = (bf16_t*)(ws + alloc((size_t)E_ * I_ * H_ * 2));
    bf16_t* W2t      = (bf16_t*)(ws + alloc((size_t)E_ * I_ * H_ * 2));
    bf16_t* fusedbuf = (bf16_t*)(ws + alloc((size_t)PAIRS * I_ * 2));
    bf16_t* ybuf     = (bf16_t*)(ws + alloc((size_t)PAIRS * H_ * 2));

    hipMemsetAsync(counts, 0, E_ * 4, stream);

    router_kernel<<<TOK / 4, 256, 0, stream>>>(x, Wg, top2e, top2w, counts, xb);
    scanfill_kernel<<<1, 256, 0, stream>>>(counts, offsets, blk_e, blk_m0, nblk,
                                           top2e, pair_tok, inv);
    wtrans_kernel<<<dim3(256, 24), 256, 0, stream>>>(W11, W12, W2, W11t, W12t, W2t);

    gemm1_kernel<<<dim3(I_ / 128, MAXBLK), 256, 0, stream>>>(
        xb, W11t, W12t, counts, offsets, blk_e, blk_m0, nblk, pair_tok, fusedbuf);
    gemm2_kernel<<<dim3(H_ / 128, MAXBLK), 256, 0, stream>>>(
        fusedbuf, W2t, counts, offsets, blk_e, blk_m0, nblk, ybuf);
    combine_kernel<<<TOK, 256, 0, stream>>>(ybuf, inv, top2w, out);
}

// Round 4
// 522.492 us; speedup vs baseline: 1.0290x; 1.0290x over previous
//
#include <hip/hip_runtime.h>
#include <hip/hip_bf16.h>
#include <stdint.h>

#define B_ 2
#define S_ 2048
#define H_ 1024
#define I_ 2048
#define E_ 8
#define TOK (B_*S_)      // 4096 tokens
#define PAIRS (TOK*2)    // 8192 token-expert pairs
#define MAXBLK 80        // max sum_e ceil(cnt_e/128) = 64+7=71

typedef __bf16 bf16_t;
typedef __bf16 bf16x4 __attribute__((ext_vector_type(4)));
typedef __bf16 bf16x8 __attribute__((ext_vector_type(8)));
typedef float  f32x4  __attribute__((ext_vector_type(4)));
typedef float  f32x16 __attribute__((ext_vector_type(16)));

// async global->LDS, 16B per lane. LDS dest = wave-uniform base + lane*16.
__device__ __forceinline__ void gl_lds16(const bf16_t* g, bf16_t* l) {
    __builtin_amdgcn_global_load_lds(
        (const __attribute__((address_space(1))) unsigned int*)g,
        (__attribute__((address_space(3))) unsigned int*)l, 16, 0, 0);
}

// compiler memory fence (zero instructions) — raw s_barrier has no compiler
// memory semantics; without these, LDS reads/writes can migrate across it.
__device__ __forceinline__ void cfence() { asm volatile("" ::: "memory"); }

// ---------------- Router (+ x -> bf16 cast fused) ----------------
__global__ void router_kernel(const float* __restrict__ x, const float* __restrict__ Wg,
                              int* __restrict__ top2e, float* __restrict__ top2w,
                              int* __restrict__ counts, bf16_t* __restrict__ xb) {
    int wave = threadIdx.x >> 6;
    int lane = threadIdx.x & 63;
    int t = blockIdx.x * 4 + wave;
    if (t >= TOK) return;
    float acc[E_];
#pragma unroll
    for (int e = 0; e < E_; e++) acc[e] = 0.f;
    const float* xrow = x + (size_t)t * H_;
    for (int j = 0; j < H_ / 64; j++) {
        int h = j * 64 + lane;
        float xv = xrow[h];
        const float4* wg = (const float4*)(Wg + (size_t)h * E_);
        float4 w0 = wg[0], w1 = wg[1];
        acc[0] += xv * w0.x; acc[1] += xv * w0.y; acc[2] += xv * w0.z; acc[3] += xv * w0.w;
        acc[4] += xv * w1.x; acc[5] += xv * w1.y; acc[6] += xv * w1.z; acc[7] += xv * w1.w;
    }
    // fused cast: write this token's bf16 row (re-read hits L1/L2)
#pragma unroll
    for (int part = 0; part < 2; part++) {
        int idx = part * 512 + lane * 8;
        float4 v0 = *(const float4*)(xrow + idx);
        float4 v1 = *(const float4*)(xrow + idx + 4);
        bf16x8 ov = { (bf16_t)v0.x, (bf16_t)v0.y, (bf16_t)v0.z, (bf16_t)v0.w,
                      (bf16_t)v1.x, (bf16_t)v1.y, (bf16_t)v1.z, (bf16_t)v1.w };
        *(bf16x8*)(xb + (size_t)t * H_ + idx) = ov;
    }
#pragma unroll
    for (int e = 0; e < E_; e++) {
#pragma unroll
        for (int m = 32; m >= 1; m >>= 1) acc[e] += __shfl_xor(acc[e], m, 64);
    }
    if (lane == 0) {
        float mx = acc[0];
        for (int e = 1; e < E_; e++) mx = fmaxf(mx, acc[e]);
        float p[E_]; float z = 0.f;
        for (int e = 0; e < E_; e++) { p[e] = __expf(acc[e] - mx); z += p[e]; }
        for (int e = 0; e < E_; e++) p[e] /= z;
        int i1 = 0; float p1 = p[0];
        for (int e = 1; e < E_; e++) if (p[e] > p1) { p1 = p[e]; i1 = e; }
        int i2 = -1; float p2 = -1.f;
        for (int e = 0; e < E_; e++) if (e != i1 && p[e] > p2) { p2 = p[e]; i2 = e; }
        float s = p1 + p2 + 1e-8f;
        top2e[t * 2]     = i1; top2e[t * 2 + 1] = i2;
        top2w[t * 2]     = p1 / s; top2w[t * 2 + 1] = p2 / s;
        atomicAdd(&counts[i1], 1);
        atomicAdd(&counts[i2], 1);
    }
}

// ---------------- scan + fill in one block (LDS cursors) ----------------
__global__ __launch_bounds__(256) void scanfill_kernel(
    const int* __restrict__ counts, int* __restrict__ offsets,
    int* __restrict__ blk_e, int* __restrict__ blk_m0, int* __restrict__ nblk,
    const int* __restrict__ top2e, int* __restrict__ pair_tok, int* __restrict__ inv) {
    __shared__ int s_cur[E_];
    if (threadIdx.x == 0) {
        int run = 0, b = 0;
        for (int e = 0; e < E_; e++) {
            offsets[e] = run; s_cur[e] = run;
            int c = counts[e];
            for (int m0 = 0; m0 < c; m0 += 128) { blk_e[b] = e; blk_m0[b] = m0; b++; }
            run += c;
        }
        nblk[0] = b;
    }
    __syncthreads();
    for (int p = threadIdx.x; p < PAIRS; p += 256) {
        int e = top2e[p];
        int pos = atomicAdd(&s_cur[e], 1);
        pair_tok[pos] = p >> 1;
        inv[p] = pos;
    }
}

// ---------------- merged weight transpose-cast ----------------
// z = w*E+e, w in {0:W11, 1:W12, 2:W2}. src [R][C] fp32 -> dst [C][R] bf16.
__global__ __launch_bounds__(256) void wtrans_kernel(
    const float* __restrict__ W11, const float* __restrict__ W12,
    const float* __restrict__ W2,
    bf16_t* __restrict__ W11t, bf16_t* __restrict__ W12t, bf16_t* __restrict__ W2t) {
    __shared__ float tile[64][129];
    int z = blockIdx.y;
    int wsel = z >> 3, e = z & 7;
    const float* sbase; bf16_t* dbase; int R, C, tx, ty;
    if (wsel == 0)      { sbase = W11; dbase = W11t; R = H_; C = I_; }
    else if (wsel == 1) { sbase = W12; dbase = W12t; R = H_; C = I_; }
    else                { sbase = W2;  dbase = W2t;  R = I_; C = H_; }
    if (wsel < 2) { tx = blockIdx.x & 15; ty = blockIdx.x >> 4; }   // 16 x 16
    else          { tx = blockIdx.x & 7;  ty = blockIdx.x >> 3; }   // 8 x 32
    const float* s = sbase + (size_t)e * R * C;
    bf16_t* d = dbase + (size_t)e * R * C;
    int c0 = tx * 128, r0 = ty * 64;
    int t = threadIdx.x;
#pragma unroll
    for (int j = 0; j < 8; j++) {
        int flat = j * 256 + t;          // 0..2047
        int r = flat >> 5;               // 0..63
        int c4 = (flat & 31) * 4;        // 0..124
        float4 v = *(const float4*)(s + (size_t)(r0 + r) * C + c0 + c4);
        tile[r][c4 + 0] = v.x;
        tile[r][c4 + 1] = v.y;
        tile[r][c4 + 2] = v.z;
        tile[r][c4 + 3] = v.w;
    }
    __syncthreads();
#pragma unroll
    for (int j = 0; j < 4; j++) {
        int flat = j * 256 + t;          // 0..1023
        int orow = flat >> 3;            // 0..127 (src col)
        int seg  = (flat & 7) * 8;       // 0..56 (src row base)
        bf16x8 v;
#pragma unroll
        for (int k = 0; k < 8; k++) v[k] = (bf16_t)tile[seg + k][orow];
        *(bf16x8*)(d + (size_t)(c0 + orow) * R + r0 + seg) = v;
    }
}

// ---------------- GEMM1: fused = SiLU(x@W11) * (x@W12) ----------------
// 256 thr / 4 waves 2x2, BM=128, BN=128 i-cols (gate+value = 256 B-rows).
// BK=32, TRIPLE-buffered LDS ring (72KB, 2 blocks/CU), ONE barrier per tile:
//   iter t: stage(t+2) -> buf[(t+2)%3]; ds_read buf[t%3]; MFMA;
//           lgkmcnt(0); vmcnt(6) [stage(t+1) landed, stage(t+2) in flight];
//           barrier.
// Swizzle (decorrelated, 64B rows): phys slot s holds global chunk
// s ^ ((row>>1)&3) -> bank quad = 4*(row&1) + slot spans all 8 quads.
__global__ __launch_bounds__(256, 2) void gemm1_kernel(
    const bf16_t* __restrict__ xb,       // [TOK][H]
    const bf16_t* __restrict__ W11t,     // [E][I][H]
    const bf16_t* __restrict__ W12t,     // [E][I][H]
    const int* __restrict__ counts, const int* __restrict__ offsets,
    const int* __restrict__ blk_e, const int* __restrict__ blk_m0,
    const int* __restrict__ nblk,
    const int* __restrict__ pair_tok,
    bf16_t* __restrict__ fused)          // [PAIRS][I]
{
    int by = blockIdx.y;
    if (by >= nblk[0]) return;
    int e = blk_e[by];
    int m0 = blk_m0[by];
    int cnt = counts[e];
    int off = offsets[e];
    int n0 = blockIdx.x * 128;           // i-col base

    __shared__ __align__(16) bf16_t la[3][128 * 32];   // 3 x 8 KB
    __shared__ __align__(16) bf16_t lb[3][256 * 32];   // 3 x 16 KB

    int tid = threadIdx.x;
    int w = tid >> 6, lane = tid & 63;
    int wm = w >> 1, wn = w & 1;
    int lrow4 = lane >> 2;               // 0..15 (row within 16-row group)
    int lcol4 = lane & 3;                // 0..3  (phys 16B slot)
    int sch   = lcol4 ^ ((lrow4 >> 1) & 3);   // decorrelated source chunk
    int r32 = lane & 31, khalf = lane >> 5;
    int rsw = (r32 >> 1) & 3;            // read-side swizzle term

    // staging pointers (per-lane global source, +k0 each tile)
    const bf16_t* aptr[2];
    const bf16_t* bptr[4];
#pragma unroll
    for (int it = 0; it < 2; it++) {
        int r = it * 64 + w * 16 + lrow4;     // 0..127
        int grow = m0 + r;
        int tok = pair_tok[off + (grow < cnt ? grow : 0)];
        aptr[it] = xb + (size_t)tok * H_ + sch * 8;
    }
#pragma unroll
    for (int it = 0; it < 4; it++) {
        int r = it * 64 + w * 16 + lrow4;     // 0..255 (0-127 gate, 128-255 value)
        const bf16_t* base = (r < 128)
            ? (W11t + ((size_t)e * I_ + n0 + r) * H_)
            : (W12t + ((size_t)e * I_ + n0 + (r - 128)) * H_);
        bptr[it] = base + sch * 8;
    }

    f32x16 acc[2][4];
#pragma unroll
    for (int a = 0; a < 2; a++)
#pragma unroll
        for (int b = 0; b < 4; b++) acc[a][b] = (f32x16)(0.f);

    // prologue: stage tiles 0,1 into buf 0,1
#pragma unroll
    for (int it = 0; it < 2; it++) gl_lds16(aptr[it], &la[0][(it * 64 + w * 16) * 32]);
#pragma unroll
    for (int it = 0; it < 4; it++) gl_lds16(bptr[it], &lb[0][(it * 64 + w * 16) * 32]);
#pragma unroll
    for (int it = 0; it < 2; it++) gl_lds16(aptr[it] + 32, &la[1][(it * 64 + w * 16) * 32]);
#pragma unroll
    for (int it = 0; it < 4; it++) gl_lds16(bptr[it] + 32, &lb[1][(it * 64 + w * 16) * 32]);
    asm volatile("s_waitcnt vmcnt(6)" ::: "memory");   // tile 0 landed, tile 1 in flight
    __builtin_amdgcn_s_barrier();
    __builtin_amdgcn_sched_barrier(0);
    cfence();

    const int NT = H_ / 32;              // 32 K-tiles
    int bcur = 0;
    for (int t = 0; t < NT; t++) {
        // stage tile t+2 into buf[(t+2)%3] (that buffer's readers finished
        // before the PREVIOUS barrier -> single-barrier epoch is safe)
        if (t + 2 < NT) {
            int bnxt = bcur + 2; if (bnxt >= 3) bnxt -= 3;
            int ko = (t + 2) * 32;
#pragma unroll
            for (int it = 0; it < 2; it++) gl_lds16(aptr[it] + ko, &la[bnxt][(it * 64 + w * 16) * 32]);
#pragma unroll
            for (int it = 0; it < 4; it++) gl_lds16(bptr[it] + ko, &lb[bnxt][(it * 64 + w * 16) * 32]);
        }

        const bf16_t* A = la[bcur];
        const bf16_t* Bb = lb[bcur];
#pragma unroll
        for (int t16 = 0; t16 < 2; t16++) {
            int seg = t16 * 2 + khalf;       // 0..3
            bf16x8 af[2], bfr[4];
#pragma unroll
            for (int ms = 0; ms < 2; ms++) {
                int row = wm * 64 + ms * 32 + r32;
                af[ms] = *(const bf16x8*)&A[row * 32 + (seg ^ rsw) * 8];
            }
#pragma unroll
            for (int ns = 0; ns < 2; ns++) {
                int browg = wn * 64 + ns * 32 + r32;
                bfr[ns]     = *(const bf16x8*)&Bb[browg * 32 + (seg ^ rsw) * 8];
                bfr[ns + 2] = *(const bf16x8*)&Bb[(browg + 128) * 32 + (seg ^ rsw) * 8];
            }
#pragma unroll
            for (int ms = 0; ms < 2; ms++)
#pragma unroll
                for (int ns = 0; ns < 4; ns++)
                    acc[ms][ns] = __builtin_amdgcn_mfma_f32_32x32x16_bf16(
                        af[ms], bfr[ns], acc[ms][ns], 0, 0, 0);
        }
        // my ds_reads of buf[t] serviced before the barrier releases it
        asm volatile("s_waitcnt lgkmcnt(0)" ::: "memory");
        // counted: stage(t+1) landed (readable next iter); stage(t+2) in flight
        if (t + 2 < NT) { asm volatile("s_waitcnt vmcnt(6)" ::: "memory"); }
        else            { asm volatile("s_waitcnt vmcnt(0)" ::: "memory"); }
        __builtin_amdgcn_sched_barrier(0);
        __builtin_amdgcn_s_barrier();
        cfence();
        bcur++; if (bcur >= 3) bcur = 0;
    }

    // C/D 32x32 layout: col=lane&31, row=(reg&3)+8*(reg>>2)+4*(lane>>5)
#pragma unroll
    for (int ms = 0; ms < 2; ms++) {
#pragma unroll
        for (int ns = 0; ns < 2; ns++) {
            int i = n0 + wn * 64 + ns * 32 + r32;
#pragma unroll
            for (int reg = 0; reg < 16; reg++) {
                int rrow = (reg & 3) + 8 * (reg >> 2) + 4 * khalf;
                int grow = m0 + wm * 64 + ms * 32 + rrow;
                if (grow < cnt) {
                    float g = acc[ms][ns][reg];
                    float v = acc[ms][ns + 2][reg];
                    float f = g * v / (1.f + __expf(-g));
                    fused[(size_t)(off + grow) * I_ + i] = (bf16_t)f;
                }
            }
        }
    }
}

// ---------------- GEMM2: y[slot] = fused[slot] @ W2, bf16 out ----------------
// Same 3-buffer single-barrier template: BK=32, 48KB LDS, 3 blocks/CU, vmcnt(4).
__global__ __launch_bounds__(256, 3) void gemm2_kernel(
    const bf16_t* __restrict__ fused,    // [PAIRS][I]
    const bf16_t* __restrict__ W2t,      // [E][H][I]
    const int* __restrict__ counts, const int* __restrict__ offsets,
    const int* __restrict__ blk_e, const int* __restrict__ blk_m0,
    const int* __restrict__ nblk,
    bf16_t* __restrict__ y)              // [PAIRS][H]
{
    int by = blockIdx.y;
    if (by >= nblk[0]) return;
    int e = blk_e[by];
    int m0 = blk_m0[by];
    int cnt = counts[e];
    int off = offsets[e];
    int n0 = blockIdx.x * 128;

    __shared__ __align__(16) bf16_t la[3][128 * 32];   // 3 x 8 KB
    __shared__ __align__(16) bf16_t lb[3][128 * 32];   // 3 x 8 KB

    int tid = threadIdx.x;
    int w = tid >> 6, lane = tid & 63;
    int wm = w >> 1, wn = w & 1;
    int lrow4 = lane >> 2;
    int lcol4 = lane & 3;
    int sch   = lcol4 ^ ((lrow4 >> 1) & 3);
    int r32 = lane & 31, khalf = lane >> 5;
    int rsw = (r32 >> 1) & 3;

    const bf16_t* aptr[2];
    const bf16_t* bptr[2];
#pragma unroll
    for (int it = 0; it < 2; it++) {
        int r = it * 64 + w * 16 + lrow4;     // 0..127
        int grow = m0 + r;
        if (grow >= cnt) grow = cnt - 1;
        aptr[it] = fused + (size_t)(off + grow) * I_ + sch * 8;
        bptr[it] = W2t + ((size_t)e * H_ + n0 + r) * I_ + sch * 8;
    }

    f32x16 acc[2][2];
#pragma unroll
    for (int a = 0; a < 2; a++)
#pragma unroll
        for (int b = 0; b < 2; b++) acc[a][b] = (f32x16)(0.f);

    // prologue: stage tiles 0,1
#pragma unroll
    for (int it = 0; it < 2; it++) {
        gl_lds16(aptr[it], &la[0][(it * 64 + w * 16) * 32]);
        gl_lds16(bptr[it], &lb[0][(it * 64 + w * 16) * 32]);
    }
#pragma unroll
    for (int it = 0; it < 2; it++) {
        gl_lds16(aptr[it] + 32, &la[1][(it * 64 + w * 16) * 32]);
        gl_lds16(bptr[it] + 32, &lb[1][(it * 64 + w * 16) * 32]);
    }
    asm volatile("s_waitcnt vmcnt(4)" ::: "memory");
    __builtin_amdgcn_s_barrier();
    __builtin_amdgcn_sched_barrier(0);
    cfence();

    const int NT = I_ / 32;              // 64 K-tiles
    int bcur = 0;
    for (int t = 0; t < NT; t++) {
        if (t + 2 < NT) {
            int bnxt = bcur + 2; if (bnxt >= 3) bnxt -= 3;
            int ko = (t + 2) * 32;
#pragma unroll
            for (int it = 0; it < 2; it++) {
                gl_lds16(aptr[it] + ko, &la[bnxt][(it * 64 + w * 16) * 32]);
                gl_lds16(bptr[it] + ko, &lb[bnxt][(it * 64 + w * 16) * 32]);
            }
        }

        const bf16_t* A = la[bcur];
        const bf16_t* Bb = lb[bcur];
#pragma unroll
        for (int t16 = 0; t16 < 2; t16++) {
            int seg = t16 * 2 + khalf;
            bf16x8 af[2], bfr[2];
#pragma unroll
            for (int ms = 0; ms < 2; ms++) {
                int row = wm * 64 + ms * 32 + r32;
                af[ms] = *(const bf16x8*)&A[row * 32 + (seg ^ rsw) * 8];
            }
#pragma unroll
            for (int ns = 0; ns < 2; ns++) {
                int brow = wn * 64 + ns * 32 + r32;
                bfr[ns] = *(const bf16x8*)&Bb[brow * 32 + (seg ^ rsw) * 8];
            }
#pragma unroll
            for (int ms = 0; ms < 2; ms++)
#pragma unroll
                for (int ns = 0; ns < 2; ns++)
                    acc[ms][ns] = __builtin_amdgcn_mfma_f32_32x32x16_bf16(
                        af[ms], bfr[ns], acc[ms][ns], 0, 0, 0);
        }
        asm volatile("s_waitcnt lgkmcnt(0)" ::: "memory");
        if (t + 2 < NT) { asm volatile("s_waitcnt vmcnt(4)" ::: "memory"); }
        else            { asm volatile("s_waitcnt vmcnt(0)" ::: "memory"); }
        __builtin_amdgcn_sched_barrier(0);
        __builtin_amdgcn_s_barrier();
        cfence();
        bcur++; if (bcur >= 3) bcur = 0;
    }

#pragma unroll
    for (int ms = 0; ms < 2; ms++) {
#pragma unroll
        for (int reg = 0; reg < 16; reg++) {
            int rrow = (reg & 3) + 8 * (reg >> 2) + 4 * khalf;
            int grow = m0 + wm * 64 + ms * 32 + rrow;
            if (grow < cnt) {
                int slot = off + grow;
#pragma unroll
                for (int ns = 0; ns < 2; ns++) {
                    int h = n0 + wn * 64 + ns * 32 + r32;
                    y[(size_t)slot * H_ + h] = (bf16_t)acc[ms][ns][reg];
                }
            }
        }
    }
}

// ---------------- combine: out[t] = w1*y[s1] + w2*y[s2] ----------------
__global__ __launch_bounds__(256) void combine_kernel(
    const bf16_t* __restrict__ y, const int* __restrict__ inv,
    const float* __restrict__ top2w, float* __restrict__ out) {
    int t = blockIdx.x;
    int h = threadIdx.x * 4;
    int s1 = inv[t * 2], s2 = inv[t * 2 + 1];
    float w1 = top2w[t * 2], w2 = top2w[t * 2 + 1];
    bf16x4 a = *(const bf16x4*)(y + (size_t)s1 * H_ + h);
    bf16x4 b = *(const bf16x4*)(y + (size_t)s2 * H_ + h);
    f32x4 r;
#pragma unroll
    for (int k = 0; k < 4; k++) r[k] = w1 * (float)a[k] + w2 * (float)b[k];
    *(f32x4*)(out + (size_t)t * H_ + h) = r;
}

// ---------------- host ----------------
extern "C" void kernel_launch(void* const* d_in, const int* in_sizes, int n_in,
                              void* d_out, int out_size, void* d_ws, size_t ws_size,
                              hipStream_t stream) {
    const float* x   = (const float*)d_in[0];
    const float* Wg  = (const float*)d_in[1];
    const float* W11 = (const float*)d_in[2];
    const float* W12 = (const float*)d_in[3];
    const float* W2  = (const float*)d_in[4];
    float* out = (float*)d_out;

    char* ws = (char*)d_ws;
    size_t o = 0;
    auto alloc = [&](size_t bytes) { size_t r = o; o = (o + bytes + 255) & ~(size_t)255; return r; };
    int*    counts   = (int*)(ws + alloc(E_ * 4));
    int*    offsets  = (int*)(ws + alloc(E_ * 4));
    int*    blk_e    = (int*)(ws + alloc(MAXBLK * 4));
    int*    blk_m0   = (int*)(ws + alloc(MAXBLK * 4));
    int*    nblk     = (int*)(ws + alloc(4));
    int*    top2e    = (int*)(ws + alloc(TOK * 2 * 4));
    float*  top2w    = (float*)(ws + alloc(TOK * 2 * 4));
    int*    pair_tok = (int*)(ws + alloc(PAIRS * 4));
    int*    inv      = (int*)(ws + alloc(TOK * 2 * 4));
    bf16_t* xb       = (bf16_t*)(ws + alloc((size_t)TOK * H_ * 2));
    bf16_t* W11t     = (bf16_t*)(ws + alloc((size_t)E_ * I_ * H_ * 2));
    bf16_t* W12t     = (bf16_t*)(ws + alloc((size_t)E_ * I_ * H_ * 2));
    bf16_t* W2t      = (bf16_t*)(ws + alloc((size_t)E_ * I_ * H_ * 2));
    bf16_t* fusedbuf = (bf16_t*)(ws + alloc((size_t)PAIRS * I_ * 2));
    bf16_t* ybuf     = (bf16_t*)(ws + alloc((size_t)PAIRS * H_ * 2));

    hipMemsetAsync(counts, 0, E_ * 4, stream);

    router_kernel<<<TOK / 4, 256, 0, stream>>>(x, Wg, top2e, top2w, counts, xb);
    scanfill_kernel<<<1, 256, 0, stream>>>(counts, offsets, blk_e, blk_m0, nblk,
                                           top2e, pair_tok, inv);
    wtrans_kernel<<<dim3(256, 24), 256, 0, stream>>>(W11, W12, W2, W11t, W12t, W2t);

    gemm1_kernel<<<dim3(I_ / 128, MAXBLK), 256, 0, stream>>>(
        xb, W11t, W12t, counts, offsets, blk_e, blk_m0, nblk, pair_tok, fusedbuf);
    gemm2_kernel<<<dim3(H_ / 128, MAXBLK), 256, 0, stream>>>(
        fusedbuf, W2t, counts, offsets, blk_e, blk_m0, nblk, ybuf);
    combine_kernel<<<TOK, 256, 0, stream>>>(ybuf, inv, top2w, out);
}